// Round 11
// baseline (193.032 us; speedup 1.0000x reference)
//
#include <hip/hip_runtime.h>
#include <stdint.h>

// MeshPoolFace: batched segment-mean pooling.
// fe: [B=16, C=256, F=16000] f32, gid: [B, F] int32 in [0, T=8000)
// out[b][c][t] = mean over {f : gid[b][f]==t} of fe[b][c][f]
//
// Round-18: r17 quad-pack REGRESSED (124.7 vs r16's 106.6): single-buffer
// serialization beat the per-op amortization -> overlap structure (dbuf,
// 1 barrier/window) is worth more than fewer LDS ops. Pool reverted to r16
// byte-for-byte. This round deletes DISPATCH overhead instead: 5 dispatches
// (memset512K, hist, scan, invperm, pool) -> 3 (memset 32B barrier words,
// fused preproc, pool). Fused preproc = one persistent kernel, grid=256
// (1 small block/CU, co-resident by construction), phases {zero-cnt, hist,
// scan, invperm} separated by device-scope release/acquire spin barriers
// (standard cooperative grid.sync pattern). Workspace is re-poisoned per
// iteration, so barrier words are memset to 0 (32 B) each launch.

#define NB 16
#define NC 256
#define NF 16000
#define NT 8000
#define CPB 16  // channels per pool block (8 pair-windows); grid = 256

typedef unsigned int uint;
typedef unsigned short ushort;
typedef float f32x4 __attribute__((ext_vector_type(4)));

__device__ __forceinline__ float bf2f(uint h) { return __uint_as_float(h << 16); }
__device__ __forceinline__ uint cvtpk(float lo, float hi) {
    uint r;
    asm("v_cvt_pk_bf16_f32 %0, %1, %2" : "=v"(r) : "v"(lo), "v"(hi));
    return r;
}

// ---------- fused preprocessing (grid = 256 x 256 thr) ----------

// Device-scope grid barrier: counter+flag pair at bar[0],bar[1] (pre-zeroed).
// Only thread 0 spins; release/acquire at agent scope orders the phases'
// plain global stores/loads across XCDs (cooperative grid.sync pattern).
__device__ __forceinline__ void gbar(uint* bar) {
    __syncthreads();
    if (threadIdx.x == 0) {
        uint old = __hip_atomic_fetch_add(&bar[0], 1u, __ATOMIC_ACQ_REL,
                                          __HIP_MEMORY_SCOPE_AGENT);
        if (old == 255u) {
            __hip_atomic_store(&bar[1], 1u, __ATOMIC_RELEASE,
                               __HIP_MEMORY_SCOPE_AGENT);
        } else {
            while (__hip_atomic_load(&bar[1], __ATOMIC_ACQUIRE,
                                     __HIP_MEMORY_SCOPE_AGENT) == 0u)
                __builtin_amdgcn_s_sleep(2);
        }
        __threadfence();   // belt-and-braces acquire of peers' writes
    }
    __syncthreads();
}

__global__ __launch_bounds__(256) void preproc_kernel(const int* __restrict__ gid,
                                                      int* __restrict__ cnt,
                                                      uint* __restrict__ pk,
                                                      uint* __restrict__ cursor,
                                                      ushort* __restrict__ sp,
                                                      uint* __restrict__ bar) {
    __shared__ int partial[256];
    const int blk = blockIdx.x, tid = threadIdx.x;

    // phase 0: zero cnt (NB*NT ints = 128000 u32; 500 per block).
    // Agent-scope relaxed stores so phase-1 RMWs (coherent point) see zeros.
    {
        uint* c = (uint*)cnt;
        int base = blk * 500;
        __hip_atomic_store(&c[base + tid], 0u, __ATOMIC_RELAXED,
                           __HIP_MEMORY_SCOPE_AGENT);
        if (tid < 244)
            __hip_atomic_store(&c[base + 256 + tid], 0u, __ATOMIC_RELAXED,
                               __HIP_MEMORY_SCOPE_AGENT);
    }
    gbar(bar + 0);

    // phase 1: histogram. 64000 int4 total; 250 per block.
    if (tid < 250) {
        int i = blk * 250 + tid;
        int4 g = ((const int4*)gid)[i];
        int* c = cnt + (i / (NF / 4)) * NT;
        atomicAdd(&c[g.x], 1);
        atomicAdd(&c[g.y], 1);
        atomicAdd(&c[g.z], 1);
        atomicAdd(&c[g.w], 1);
    }
    gbar(bar + 2);

    // phase 2: per-batch exclusive scan (blocks 0..15), write pk + cursor.
    if (blk < NB) {
        const int b = blk;
        const int* cb_ = cnt + b * NT;
        int loc[32], nv[32];
        int ts = 0;
        if (tid < 250) {
            const int4* c4 = (const int4*)(cb_ + 32 * tid);
#pragma unroll
            for (int j = 0; j < 8; ++j) {
                int4 v = c4[j];
                loc[4 * j + 0] = ts; nv[4 * j + 0] = v.x; ts += v.x;
                loc[4 * j + 1] = ts; nv[4 * j + 1] = v.y; ts += v.y;
                loc[4 * j + 2] = ts; nv[4 * j + 2] = v.z; ts += v.z;
                loc[4 * j + 3] = ts; nv[4 * j + 3] = v.w; ts += v.w;
            }
        }
        partial[tid] = (tid < 250) ? ts : 0;
        __syncthreads();

        if (tid < 64) {
            int s0 = partial[4 * tid], s1 = partial[4 * tid + 1];
            int s2 = partial[4 * tid + 2], s3 = partial[4 * tid + 3];
            int lsum = s0 + s1 + s2 + s3;
            int inc = lsum;
            for (int d = 1; d < 64; d <<= 1) {
                int u = __shfl_up(inc, d);
                if (tid >= d) inc += u;
            }
            int exc = inc - lsum;
            partial[4 * tid + 0] = exc;
            partial[4 * tid + 1] = exc + s0;
            partial[4 * tid + 2] = exc + s0 + s1;
            partial[4 * tid + 3] = exc + s0 + s1 + s2;
        }
        __syncthreads();

        if (tid < 250) {
            int base = partial[tid];
            uint* pkb = pk + (size_t)b * NT + 32 * tid;
            uint* cb = cursor + (size_t)b * NT + 32 * tid;
#pragma unroll
            for (int j = 0; j < 32; ++j) {
                uint o = (uint)(base + loc[j]);
                pkb[j] = o | ((uint)nv[j] << 14);   // off<16384, n<2^18
                cb[j] = o;
            }
        }
    }
    gbar(bar + 4);

    // phase 3: inverse permutation sp[b][f] = off[g] + occurrence.
    // blk = b*16 + q; 1000 faces (250 int4) per block.
    if (tid < 250) {
        const int b = blk >> 4, q = blk & 15;
        const int4* g4 = (const int4*)(gid + (size_t)b * NF + q * 1000);
        uint* cb = cursor + (size_t)b * NT;
        uint2* sp2 = (uint2*)(sp + (size_t)b * NF + q * 1000);
        int4 g = g4[tid];
        uint p0 = atomicAdd(&cb[g.x], 1u);
        uint p1 = atomicAdd(&cb[g.y], 1u);
        uint p2 = atomicAdd(&cb[g.z], 1u);
        uint p3 = atomicAdd(&cb[g.w], 1u);
        sp2[tid] = make_uint2(p0 | (p1 << 16), p2 | (p3 << 16));
    }
}

// ---------- pool (r16 champion, unchanged) ----------

// Raw barrier: drain own LDS ops, workgroup barrier. Never drains vmcnt,
// so global prefetch loads / NT stores stay in flight across it.
#define LGKM_BAR() do {                                          \
        asm volatile("s_waitcnt lgkmcnt(0)" ::: "memory");       \
        __builtin_amdgcn_s_barrier();                            \
        __builtin_amdgcn_sched_barrier(0);                       \
    } while (0)

// K4: pair-packed pool, double-buffered fes32, direct coalesced store.
// grid = 256, 1024 thr, 128000 B dynamic LDS (2 x 64000 fes buffers).
// Per window: scatter pair k -> buf(k&1) / prefetch k+1 / LGKM_BAR /
// gather buf(k&1) + NT dword stores to out. One barrier per window.
__global__ __launch_bounds__(1024) void pool_kernel(const float* __restrict__ fe,
                                                    const ushort* __restrict__ sp,
                                                    const uint* __restrict__ pk,
                                                    float* __restrict__ out) {
    extern __shared__ char smem[];
    uint* fes32 = (uint*)smem;   // 2 x 16000 u32: packed 2ch bf16 per face
    const int bid = blockIdx.x;
    const int b = bid >> 4, cg = bid & 15;
    const int tid = threadIdx.x;
    const size_t bc0 = (size_t)(b * NC + cg * CPB);
    const bool t3 = (tid < 928);     // face tail: 4000 f32x4 per channel
    const bool t8 = (tid < 832);     // group tail: 8000 groups
    const int tl = t3 ? tid + 3072 : tid;   // uniform-load index (dummy=tid)

    // Register-cache inverse permutation (slot indices, packed u16 pairs)
    const uint2* sp2 = (const uint2*)(sp + (size_t)b * NF);
    uint2 s0 = sp2[tid];
    uint2 s1 = sp2[tid + 1024];
    uint2 s2 = sp2[tid + 2048];
    uint2 s3 = sp2[tl];   // garbage for !t3, never written

    // Register-cache pk (groups t = {tid+it*1024, it<7} + {7168+tid,<832})
    const uint* pkb = pk + (size_t)b * NT;
    uint pv[8];
#pragma unroll
    for (int it = 0; it < 7; ++it) pv[it] = pkb[tid + it * 1024];
    pv[7] = 0;
    if (t8) pv[7] = pkb[7168 + tid];

    const f32x4* fe4base = (const f32x4*)(fe + bc0 * NF);
    f32x4 a0, a1, a2, a3, b0, b1, b2, b3;

    // prologue: issue pair-0 loads (channels 0,1) — plain loads (L3 hits)
    {
        const f32x4* fA = fe4base;
        const f32x4* fB = fe4base + (NF / 4);
        a0 = fA[tid]; a1 = fA[tid + 1024]; a2 = fA[tid + 2048]; a3 = fA[tl];
        b0 = fB[tid]; b1 = fB[tid + 1024]; b2 = fB[tid + 2048]; b3 = fB[tl];
    }

#define PAIR_WRITE(F, S, VA, VB) do {                                    \
        (F)[(S).x & 0xFFFFu] = cvtpk((VA)[0], (VB)[0]);                  \
        (F)[(S).x >> 16]     = cvtpk((VA)[1], (VB)[1]);                  \
        (F)[(S).y & 0xFFFFu] = cvtpk((VA)[2], (VB)[2]);                  \
        (F)[(S).y >> 16]     = cvtpk((VA)[3], (VB)[3]);                  \
    } while (0)

// Paired gather + direct coalesced NT dword stores (consecutive t across
// consecutive threads -> wave stores 256B contiguous, full lines).
#define GATHER_ST(F, P, T) do {                                          \
        uint p_ = (P);                                                   \
        uint off_ = p_ & 0x3FFFu, n_ = p_ >> 14;                         \
        float sa_ = 0.f, sb_ = 0.f;                                      \
        uint r_ = 0;                                                     \
        for (; r_ + 2 <= n_; r_ += 2) {                                  \
            uint2 w_;                                                    \
            __builtin_memcpy(&w_, &(F)[off_ + r_], 8);                   \
            sa_ += bf2f(w_.x & 0xFFFFu) + bf2f(w_.y & 0xFFFFu);          \
            sb_ += bf2f(w_.x >> 16) + bf2f(w_.y >> 16);                  \
        }                                                                \
        if (r_ < n_) {                                                   \
            uint w_ = (F)[off_ + r_];                                    \
            sa_ += bf2f(w_ & 0xFFFFu);                                   \
            sb_ += bf2f(w_ >> 16);                                       \
        }                                                                \
        float rn_ = n_ ? __builtin_amdgcn_rcpf((float)n_) : 0.f;         \
        __builtin_nontemporal_store(sa_ * rn_, &oA[T]);                  \
        __builtin_nontemporal_store(sb_ * rn_, &oB[T]);                  \
    } while (0)

#pragma unroll
    for (int k = 0; k < CPB / 2; ++k) {
        uint* F = fes32 + (k & 1) * 16000;

        // scatter pair k into buf(k&1); gather(k-1) read buf((k-1)&1) — no
        // conflict; barrier at window k-1 ordered gather(k-2) before this.
        PAIR_WRITE(F, s0, a0, b0);
        PAIR_WRITE(F, s1, a1, b1);
        PAIR_WRITE(F, s2, a2, b2);
        if (t3) PAIR_WRITE(F, s3, a3, b3);

        // prefetch next pair: uniform 8 loads, in flight across the window
        if (k + 1 < CPB / 2) {
            const f32x4* fA = fe4base + (size_t)(2 * k + 2) * (NF / 4);
            const f32x4* fB = fA + (NF / 4);
            a0 = fA[tid]; a1 = fA[tid + 1024]; a2 = fA[tid + 2048]; a3 = fA[tl];
            b0 = fB[tid]; b1 = fB[tid + 1024]; b2 = fB[tid + 2048]; b3 = fB[tl];
        }

        LGKM_BAR();   // scatter(k) visible to all; gather(k-1) complete too

        // gather + store means for both channels of pair k
        float* oA = out + (bc0 + (size_t)(2 * k)) * NT;
        float* oB = out + (bc0 + (size_t)(2 * k + 1)) * NT;
#pragma unroll
        for (int it = 0; it < 7; ++it) GATHER_ST(F, pv[it], tid + it * 1024);
        if (t8) GATHER_ST(F, pv[7], 7168 + tid);
    }
#undef GATHER_ST
#undef PAIR_WRITE
}

// Fallback (round-2 path) if workspace is too small.
__device__ __forceinline__ void lds_fadd(unsigned addr, float v) {
    asm volatile("ds_add_f32 %0, %1" :: "v"(addr), "v"(v));
}
__global__ __launch_bounds__(256) void pool_fused_kernel(const float* __restrict__ fe,
                                                         const int* __restrict__ gid,
                                                         float* __restrict__ out) {
    __shared__ float acc[NT];
    __shared__ int cnt[NT];
    const int bc = blockIdx.x, b = bc >> 8, tid = threadIdx.x;
    for (int t = tid; t < NT; t += 256) { acc[t] = 0.0f; cnt[t] = 0; }
    __syncthreads();
    const unsigned accb = (unsigned)(uintptr_t)acc;
    const float4* fe4 = (const float4*)(fe + (size_t)bc * NF);
    const int4* gid4 = (const int4*)(gid + (size_t)b * NF);
    for (int i = tid; i < NF / 4; i += 256) {
        float4 v = fe4[i];
        int4 g = gid4[i];
        lds_fadd(accb + 4u * (unsigned)g.x, v.x); atomicAdd(&cnt[g.x], 1);
        lds_fadd(accb + 4u * (unsigned)g.y, v.y); atomicAdd(&cnt[g.y], 1);
        lds_fadd(accb + 4u * (unsigned)g.z, v.z); atomicAdd(&cnt[g.z], 1);
        lds_fadd(accb + 4u * (unsigned)g.w, v.w); atomicAdd(&cnt[g.w], 1);
    }
    asm volatile("s_waitcnt lgkmcnt(0)" ::: "memory");
    __syncthreads();
    float* orow = out + (size_t)bc * NT;
    for (int t = tid; t < NT; t += 256) {
        int n = cnt[t];
        orow[t] = acc[t] / (float)(n > 0 ? n : 1);
    }
}

extern "C" void kernel_launch(void* const* d_in, const int* in_sizes, int n_in,
                              void* d_out, int out_size, void* d_ws, size_t ws_size,
                              hipStream_t stream) {
    const float* fe = (const float*)d_in[0];
    const int* gid = (const int*)d_in[1];
    float* out = (float*)d_out;

    // workspace layout (bytes)
    const size_t O_CNT = 0;          // int [NB*NT]   512000
    const size_t O_CUR = 512000;     // u32 [NB*NT]   512000
    const size_t O_PK  = 1024000;    // u32 [NB*NT]   512000
    const size_t O_SP  = 1536000;    // u16 [NB*NF]   512000
    const size_t O_BAR = 2048000;    // u32 [8]       32 (3 barriers x 2)
    const size_t TOTAL = 2048032;

    if (ws_size >= TOTAL) {
        char* w = (char*)d_ws;
        int* cnt = (int*)(w + O_CNT);
        uint* cursor = (uint*)(w + O_CUR);
        uint* pk = (uint*)(w + O_PK);
        ushort* sp = (ushort*)(w + O_SP);
        uint* bar = (uint*)(w + O_BAR);

        static bool lds_opted = false;
        if (!lds_opted) {
            (void)hipFuncSetAttribute((const void*)pool_kernel,
                                      hipFuncAttributeMaxDynamicSharedMemorySize,
                                      128000);
            lds_opted = true;
        }

        (void)hipMemsetAsync(bar, 0, 32, stream);
        preproc_kernel<<<256, 256, 0, stream>>>(gid, cnt, pk, cursor, sp, bar);
        pool_kernel<<<NB * (NC / CPB), 1024, 128000, stream>>>(fe, sp, pk, out);
    } else {
        pool_fused_kernel<<<NB * NC, 256, 0, stream>>>(fe, gid, out);
    }
}

// Round 12
// 104.715 us; speedup vs baseline: 1.8434x; 1.8434x over previous
//
#include <hip/hip_runtime.h>
#include <stdint.h>

// MeshPoolFace: batched segment-mean pooling.
// fe: [B=16, C=256, F=16000] f32, gid: [B, F] int32 in [0, T=8000)
// out[b][c][t] = mean over {f : gid[b][f]==t} of fe[b][c][f]
//
// Round-19: r18's fused-preproc REGRESSED (193us): single-line agent-scope
// grid barriers serialize through the cross-XCD coherence point (~30us per
// barrier; per-XCD L2s non-coherent). Lesson: contended device-scope sync
// on MI355X is ~10x worse than naive models (matches r11's scatter-add).
// This round cuts a dispatch with ZERO new synchronization: fuse scan into
// invperm via redundant recomputation — each of the 256 invperm blocks
// recomputes its batch's exclusive scan privately in LDS (parallel, free),
// then slot = off_s[g] + atomicAdd(&zcursor[g],1) with zcursor zero-init
// (memset widened to 1MB, still one dispatch). q==0 blocks write pk.
// 5 dispatches -> 4. Pool = r16 champion, byte-identical.

#define NB 16
#define NC 256
#define NF 16000
#define NT 8000
#define CPB 16  // channels per pool block (8 pair-windows); grid = 256

typedef unsigned int uint;
typedef unsigned short ushort;
typedef float f32x4 __attribute__((ext_vector_type(4)));

__device__ __forceinline__ float bf2f(uint h) { return __uint_as_float(h << 16); }
__device__ __forceinline__ uint cvtpk(float lo, float hi) {
    uint r;
    asm("v_cvt_pk_bf16_f32 %0, %1, %2" : "=v"(r) : "v"(lo), "v"(hi));
    return r;
}

// K1: global histogram of group sizes. grid = 250.
__global__ __launch_bounds__(256) void hist_kernel(const int* __restrict__ gid,
                                                   int* __restrict__ cnt) {
    int i = blockIdx.x * 256 + threadIdx.x;
    if (i >= NB * NF / 4) return;
    int4 g = ((const int4*)gid)[i];
    int* c = cnt + (i / (NF / 4)) * NT;
    atomicAdd(&c[g.x], 1);
    atomicAdd(&c[g.y], 1);
    atomicAdd(&c[g.z], 1);
    atomicAdd(&c[g.w], 1);
}

// K2: fused scan+invperm. grid = NB*16 = 256, 256 thr.
// Each block: (a) redundant per-batch exclusive scan of cnt -> off_s (LDS);
// (b) q==0 blocks write pk[t] = off | n<<14; (c) invperm for its 1000
// faces: slot = off_s[g] + atomicAdd(zcursor[g], 1), zcursor zero-init.
// No grid sync: the scan is recomputed per block (parallel, ~2-3us).
__global__ __launch_bounds__(256) void scanperm_kernel(const int* __restrict__ gid,
                                                       const int* __restrict__ cnt_g,
                                                       uint* __restrict__ zc_g,
                                                       uint* __restrict__ pk,
                                                       ushort* __restrict__ sp) {
    __shared__ int off_s[NT];
    __shared__ int partial[256];
    const int blk = blockIdx.x;
    const int b = blk >> 4, q = blk & 15;
    const int tid = threadIdx.x;
    const int* cnt = cnt_g + b * NT;

    int loc[32], nv[32];
    int ts = 0;
    if (tid < 250) {
        const int4* c4 = (const int4*)(cnt + 32 * tid);
#pragma unroll
        for (int j = 0; j < 8; ++j) {
            int4 v = c4[j];
            loc[4 * j + 0] = ts; nv[4 * j + 0] = v.x; ts += v.x;
            loc[4 * j + 1] = ts; nv[4 * j + 1] = v.y; ts += v.y;
            loc[4 * j + 2] = ts; nv[4 * j + 2] = v.z; ts += v.z;
            loc[4 * j + 3] = ts; nv[4 * j + 3] = v.w; ts += v.w;
        }
    }
    partial[tid] = (tid < 250) ? ts : 0;
    __syncthreads();

    if (tid < 64) {
        int s0 = partial[4 * tid], s1 = partial[4 * tid + 1];
        int s2 = partial[4 * tid + 2], s3 = partial[4 * tid + 3];
        int lsum = s0 + s1 + s2 + s3;
        int inc = lsum;
        for (int d = 1; d < 64; d <<= 1) {
            int u = __shfl_up(inc, d);
            if (tid >= d) inc += u;
        }
        int exc = inc - lsum;
        partial[4 * tid + 0] = exc;
        partial[4 * tid + 1] = exc + s0;
        partial[4 * tid + 2] = exc + s0 + s1;
        partial[4 * tid + 3] = exc + s0 + s1 + s2;
    }
    __syncthreads();

    if (tid < 250) {
        int base = partial[tid];
#pragma unroll
        for (int j = 0; j < 32; ++j) off_s[32 * tid + j] = base + loc[j];
        if (q == 0) {
            uint* pkb = pk + (size_t)b * NT + 32 * tid;
#pragma unroll
            for (int j = 0; j < 32; ++j)
                pkb[j] = (uint)(base + loc[j]) | ((uint)nv[j] << 14);
        }
    }
    __syncthreads();

    // invperm for this block's 1000 faces (250 int4)
    if (tid < 250) {
        const int4* g4 = (const int4*)(gid + (size_t)b * NF + q * 1000);
        uint* zc = zc_g + (size_t)b * NT;
        uint2* sp2 = (uint2*)(sp + (size_t)b * NF + q * 1000);  // 8B aligned
        int4 g = g4[tid];
        uint p0 = (uint)off_s[g.x] + atomicAdd(&zc[g.x], 1u);
        uint p1 = (uint)off_s[g.y] + atomicAdd(&zc[g.y], 1u);
        uint p2 = (uint)off_s[g.z] + atomicAdd(&zc[g.z], 1u);
        uint p3 = (uint)off_s[g.w] + atomicAdd(&zc[g.w], 1u);
        sp2[tid] = make_uint2(p0 | (p1 << 16), p2 | (p3 << 16));
    }
}

// Raw barrier: drain own LDS ops, workgroup barrier. Never drains vmcnt,
// so global prefetch loads / NT stores stay in flight across it.
#define LGKM_BAR() do {                                          \
        asm volatile("s_waitcnt lgkmcnt(0)" ::: "memory");       \
        __builtin_amdgcn_s_barrier();                            \
        __builtin_amdgcn_sched_barrier(0);                       \
    } while (0)

// K4: pair-packed pool, double-buffered fes32, direct coalesced store.
// grid = 256, 1024 thr, 128000 B dynamic LDS (2 x 64000 fes buffers).
// Per window: scatter pair k -> buf(k&1) / prefetch k+1 / LGKM_BAR /
// gather buf(k&1) + NT dword stores to out. One barrier per window.
__global__ __launch_bounds__(1024) void pool_kernel(const float* __restrict__ fe,
                                                    const ushort* __restrict__ sp,
                                                    const uint* __restrict__ pk,
                                                    float* __restrict__ out) {
    extern __shared__ char smem[];
    uint* fes32 = (uint*)smem;   // 2 x 16000 u32: packed 2ch bf16 per face
    const int bid = blockIdx.x;
    const int b = bid >> 4, cg = bid & 15;
    const int tid = threadIdx.x;
    const size_t bc0 = (size_t)(b * NC + cg * CPB);
    const bool t3 = (tid < 928);     // face tail: 4000 f32x4 per channel
    const bool t8 = (tid < 832);     // group tail: 8000 groups
    const int tl = t3 ? tid + 3072 : tid;   // uniform-load index (dummy=tid)

    // Register-cache inverse permutation (slot indices, packed u16 pairs)
    const uint2* sp2 = (const uint2*)(sp + (size_t)b * NF);
    uint2 s0 = sp2[tid];
    uint2 s1 = sp2[tid + 1024];
    uint2 s2 = sp2[tid + 2048];
    uint2 s3 = sp2[tl];   // garbage for !t3, never written

    // Register-cache pk (groups t = {tid+it*1024, it<7} + {7168+tid,<832})
    const uint* pkb = pk + (size_t)b * NT;
    uint pv[8];
#pragma unroll
    for (int it = 0; it < 7; ++it) pv[it] = pkb[tid + it * 1024];
    pv[7] = 0;
    if (t8) pv[7] = pkb[7168 + tid];

    const f32x4* fe4base = (const f32x4*)(fe + bc0 * NF);
    f32x4 a0, a1, a2, a3, b0, b1, b2, b3;

    // prologue: issue pair-0 loads (channels 0,1) — plain loads (L3 hits)
    {
        const f32x4* fA = fe4base;
        const f32x4* fB = fe4base + (NF / 4);
        a0 = fA[tid]; a1 = fA[tid + 1024]; a2 = fA[tid + 2048]; a3 = fA[tl];
        b0 = fB[tid]; b1 = fB[tid + 1024]; b2 = fB[tid + 2048]; b3 = fB[tl];
    }

#define PAIR_WRITE(F, S, VA, VB) do {                                    \
        (F)[(S).x & 0xFFFFu] = cvtpk((VA)[0], (VB)[0]);                  \
        (F)[(S).x >> 16]     = cvtpk((VA)[1], (VB)[1]);                  \
        (F)[(S).y & 0xFFFFu] = cvtpk((VA)[2], (VB)[2]);                  \
        (F)[(S).y >> 16]     = cvtpk((VA)[3], (VB)[3]);                  \
    } while (0)

// Paired gather + direct coalesced NT dword stores (consecutive t across
// consecutive threads -> wave stores 256B contiguous, full lines).
#define GATHER_ST(F, P, T) do {                                          \
        uint p_ = (P);                                                   \
        uint off_ = p_ & 0x3FFFu, n_ = p_ >> 14;                         \
        float sa_ = 0.f, sb_ = 0.f;                                      \
        uint r_ = 0;                                                     \
        for (; r_ + 2 <= n_; r_ += 2) {                                  \
            uint2 w_;                                                    \
            __builtin_memcpy(&w_, &(F)[off_ + r_], 8);                   \
            sa_ += bf2f(w_.x & 0xFFFFu) + bf2f(w_.y & 0xFFFFu);          \
            sb_ += bf2f(w_.x >> 16) + bf2f(w_.y >> 16);                  \
        }                                                                \
        if (r_ < n_) {                                                   \
            uint w_ = (F)[off_ + r_];                                    \
            sa_ += bf2f(w_ & 0xFFFFu);                                   \
            sb_ += bf2f(w_ >> 16);                                       \
        }                                                                \
        float rn_ = n_ ? __builtin_amdgcn_rcpf((float)n_) : 0.f;         \
        __builtin_nontemporal_store(sa_ * rn_, &oA[T]);                  \
        __builtin_nontemporal_store(sb_ * rn_, &oB[T]);                  \
    } while (0)

#pragma unroll
    for (int k = 0; k < CPB / 2; ++k) {
        uint* F = fes32 + (k & 1) * 16000;

        // scatter pair k into buf(k&1); gather(k-1) read buf((k-1)&1) — no
        // conflict; barrier at window k-1 ordered gather(k-2) before this.
        PAIR_WRITE(F, s0, a0, b0);
        PAIR_WRITE(F, s1, a1, b1);
        PAIR_WRITE(F, s2, a2, b2);
        if (t3) PAIR_WRITE(F, s3, a3, b3);

        // prefetch next pair: uniform 8 loads, in flight across the window
        if (k + 1 < CPB / 2) {
            const f32x4* fA = fe4base + (size_t)(2 * k + 2) * (NF / 4);
            const f32x4* fB = fA + (NF / 4);
            a0 = fA[tid]; a1 = fA[tid + 1024]; a2 = fA[tid + 2048]; a3 = fA[tl];
            b0 = fB[tid]; b1 = fB[tid + 1024]; b2 = fB[tid + 2048]; b3 = fB[tl];
        }

        LGKM_BAR();   // scatter(k) visible to all; gather(k-1) complete too

        // gather + store means for both channels of pair k
        float* oA = out + (bc0 + (size_t)(2 * k)) * NT;
        float* oB = out + (bc0 + (size_t)(2 * k + 1)) * NT;
#pragma unroll
        for (int it = 0; it < 7; ++it) GATHER_ST(F, pv[it], tid + it * 1024);
        if (t8) GATHER_ST(F, pv[7], 7168 + tid);
    }
#undef GATHER_ST
#undef PAIR_WRITE
}

// Fallback (round-2 path) if workspace is too small.
__device__ __forceinline__ void lds_fadd(unsigned addr, float v) {
    asm volatile("ds_add_f32 %0, %1" :: "v"(addr), "v"(v));
}
__global__ __launch_bounds__(256) void pool_fused_kernel(const float* __restrict__ fe,
                                                         const int* __restrict__ gid,
                                                         float* __restrict__ out) {
    __shared__ float acc[NT];
    __shared__ int cnt[NT];
    const int bc = blockIdx.x, b = bc >> 8, tid = threadIdx.x;
    for (int t = tid; t < NT; t += 256) { acc[t] = 0.0f; cnt[t] = 0; }
    __syncthreads();
    const unsigned accb = (unsigned)(uintptr_t)acc;
    const float4* fe4 = (const float4*)(fe + (size_t)bc * NF);
    const int4* gid4 = (const int4*)(gid + (size_t)b * NF);
    for (int i = tid; i < NF / 4; i += 256) {
        float4 v = fe4[i];
        int4 g = gid4[i];
        lds_fadd(accb + 4u * (unsigned)g.x, v.x); atomicAdd(&cnt[g.x], 1);
        lds_fadd(accb + 4u * (unsigned)g.y, v.y); atomicAdd(&cnt[g.y], 1);
        lds_fadd(accb + 4u * (unsigned)g.z, v.z); atomicAdd(&cnt[g.z], 1);
        lds_fadd(accb + 4u * (unsigned)g.w, v.w); atomicAdd(&cnt[g.w], 1);
    }
    asm volatile("s_waitcnt lgkmcnt(0)" ::: "memory");
    __syncthreads();
    float* orow = out + (size_t)bc * NT;
    for (int t = tid; t < NT; t += 256) {
        int n = cnt[t];
        orow[t] = acc[t] / (float)(n > 0 ? n : 1);
    }
}

extern "C" void kernel_launch(void* const* d_in, const int* in_sizes, int n_in,
                              void* d_out, int out_size, void* d_ws, size_t ws_size,
                              hipStream_t stream) {
    const float* fe = (const float*)d_in[0];
    const int* gid = (const int*)d_in[1];
    float* out = (float*)d_out;

    // workspace layout (bytes)
    const size_t O_CNT = 0;          // int [NB*NT]   512000  (zeroed)
    const size_t O_ZC  = 512000;     // u32 [NB*NT]   512000  (zeroed)
    const size_t O_PK  = 1024000;    // u32 [NB*NT]   512000
    const size_t O_SP  = 1536000;    // u16 [NB*NF]   512000
    const size_t TOTAL = 2048000;

    if (ws_size >= TOTAL) {
        char* w = (char*)d_ws;
        int* cnt = (int*)(w + O_CNT);
        uint* zc = (uint*)(w + O_ZC);
        uint* pk = (uint*)(w + O_PK);
        ushort* sp = (ushort*)(w + O_SP);

        static bool lds_opted = false;
        if (!lds_opted) {
            (void)hipFuncSetAttribute((const void*)pool_kernel,
                                      hipFuncAttributeMaxDynamicSharedMemorySize,
                                      128000);
            lds_opted = true;
        }

        (void)hipMemsetAsync(w, 0, 1024000, stream);   // cnt + zcursor
        hist_kernel<<<(NB * NF / 4 + 255) / 256, 256, 0, stream>>>(gid, cnt);
        scanperm_kernel<<<NB * 16, 256, 0, stream>>>(gid, cnt, zc, pk, sp);
        pool_kernel<<<NB * (NC / CPB), 1024, 128000, stream>>>(fe, sp, pk, out);
    } else {
        pool_fused_kernel<<<NB * NC, 256, 0, stream>>>(fe, gid, out);
    }
}

// Round 13
// 93.582 us; speedup vs baseline: 2.0627x; 1.1190x over previous
//
#include <hip/hip_runtime.h>
#include <stdint.h>

// MeshPoolFace: batched segment-mean pooling.
// fe: [B=16, C=256, F=16000] f32, gid: [B, F] int32 in [0, T=8000)
// out[b][c][t] = mean over {f : gid[b][f]==t} of fe[b][c][f]
//
// Round-20: 3 dispatches; metadata never round-trips through HBM.
// Key insight: hist's atomicAdd ALREADY returns the occurrence index ->
// occ[f] = old value (packed u16x4, coalesced). scanperm deleted: each pool
// block recomputes its batch's exclusive scan privately (r19's redundant-
// recompute pattern, 1024-thr two-level shfl scan) into a 32KB LDS overlay
// of fes-buf0 (pkl[t] = off|n<<14), then derives pv and the slot packs from
// gid+occ+pkl in registers. sp/pk/zc arrays (1.5MB RW) die; memset shrinks
// to 512KB. Window loop = r16 champion, byte-identical.
// Chain: memset(512K) -> hist(+occ) -> pool.

#define NB 16
#define NC 256
#define NF 16000
#define NT 8000
#define CPB 16  // channels per pool block (8 pair-windows); grid = 256

typedef unsigned int uint;
typedef unsigned short ushort;
typedef float f32x4 __attribute__((ext_vector_type(4)));

__device__ __forceinline__ float bf2f(uint h) { return __uint_as_float(h << 16); }
__device__ __forceinline__ uint cvtpk(float lo, float hi) {
    uint r;
    asm("v_cvt_pk_bf16_f32 %0, %1, %2" : "=v"(r) : "v"(lo), "v"(hi));
    return r;
}

// K1: histogram + occurrence index. grid = 250.
// occ[f] = old count from the atomic = unique index in [0, n(g)) per face.
__global__ __launch_bounds__(256) void hist_kernel(const int* __restrict__ gid,
                                                   int* __restrict__ cnt,
                                                   ushort* __restrict__ occ) {
    int i = blockIdx.x * 256 + threadIdx.x;
    if (i >= NB * NF / 4) return;
    int4 g = ((const int4*)gid)[i];
    int* c = cnt + (i / (NF / 4)) * NT;
    uint o0 = (uint)atomicAdd(&c[g.x], 1);
    uint o1 = (uint)atomicAdd(&c[g.y], 1);
    uint o2 = (uint)atomicAdd(&c[g.z], 1);
    uint o3 = (uint)atomicAdd(&c[g.w], 1);
    ((ushort4*)occ)[i] = make_ushort4((ushort)o0, (ushort)o1,
                                      (ushort)o2, (ushort)o3);
}

// Raw barrier: drain own LDS ops, workgroup barrier. Never drains vmcnt,
// so global prefetch loads / NT stores stay in flight across it.
#define LGKM_BAR() do {                                          \
        asm volatile("s_waitcnt lgkmcnt(0)" ::: "memory");       \
        __builtin_amdgcn_s_barrier();                            \
        __builtin_amdgcn_sched_barrier(0);                       \
    } while (0)

// K4: pool with in-kernel scan prologue. grid = 256, 1024 thr, 128000 B
// dynamic LDS. Prologue: private scan of cnt[b] -> pkl LDS overlay (buf0's
// first 32KB) -> pv + slot packs in regs -> barrier -> r16 window loop
// (buf0 fully overwritten by window-0 scatter).
__global__ __launch_bounds__(1024) void pool_kernel(const float* __restrict__ fe,
                                                    const int* __restrict__ gid,
                                                    const ushort* __restrict__ occ,
                                                    const int* __restrict__ cnt,
                                                    float* __restrict__ out) {
    extern __shared__ char smem[];
    uint* fes32 = (uint*)smem;          // 2 x 16000 u32 window buffers
    uint* pkl = (uint*)smem;            // prologue overlay: pkl[8000] (32KB)
    int* wpart = (int*)(smem + 64000);  // 16 wave partials (buf1 region)
    const int bid = blockIdx.x;
    const int b = bid >> 4, cg = bid & 15;
    const int tid = threadIdx.x;
    const int lane = tid & 63, wid = tid >> 6;
    const size_t bc0 = (size_t)(b * NC + cg * CPB);
    const bool t3 = (tid < 928);     // face tail: 4000 f32x4 per channel
    const bool t8 = (tid < 832);     // group tail: 8000 groups
    const int tl = t3 ? tid + 3072 : tid;   // uniform-load index (dummy=tid)

    // ---- prologue A: block-private exclusive scan of cnt[b] -> pkl ----
    // 1000 active threads x 8 counts; two-level scan (wave shfl + partials).
    int loc[8], nv[8];
    int ts = 0;
    if (tid < 1000) {
        const int4* c4 = (const int4*)(cnt + (size_t)b * NT + 8 * tid);
        int4 v0 = c4[0], v1 = c4[1];
        loc[0] = ts; nv[0] = v0.x; ts += v0.x;
        loc[1] = ts; nv[1] = v0.y; ts += v0.y;
        loc[2] = ts; nv[2] = v0.z; ts += v0.z;
        loc[3] = ts; nv[3] = v0.w; ts += v0.w;
        loc[4] = ts; nv[4] = v1.x; ts += v1.x;
        loc[5] = ts; nv[5] = v1.y; ts += v1.y;
        loc[6] = ts; nv[6] = v1.z; ts += v1.z;
        loc[7] = ts; nv[7] = v1.w; ts += v1.w;
    }
    int inc = ts;
    for (int d = 1; d < 64; d <<= 1) {
        int u = __shfl_up(inc, d);
        if (lane >= d) inc += u;
    }
    if (lane == 63) wpart[wid] = inc;
    __syncthreads();
    {
        int wbase = 0;
        for (int wv = 0; wv < wid; ++wv) wbase += wpart[wv];  // broadcast reads
        int base = wbase + inc - ts;   // exclusive prefix for this thread
        if (tid < 1000) {
#pragma unroll
            for (int j = 0; j < 8; ++j)
                pkl[8 * tid + j] = (uint)(base + loc[j]) | ((uint)nv[j] << 14);
        }
    }
    __syncthreads();   // pkl complete

    // ---- prologue B: pv + slot packs from pkl/gid/occ ----
    uint pv[8];
#pragma unroll
    for (int it = 0; it < 7; ++it) pv[it] = pkl[tid + it * 1024];
    pv[7] = 0;
    if (t8) pv[7] = pkl[7168 + tid];

    uint2 s0, s1, s2, s3;
    {
        const int4* g4 = (const int4*)(gid + (size_t)b * NF);
        const ushort4* o4 = (const ushort4*)(occ + (size_t)b * NF);
        int4 ga = g4[tid], gb4 = g4[tid + 1024];
        int4 gc = g4[tid + 2048], gd = g4[tl];
        ushort4 oa = o4[tid], ob = o4[tid + 1024];
        ushort4 oc = o4[tid + 2048], od = o4[tl];
#define SLOT(G, O) ((pkl[(uint)(G)] & 0x3FFFu) + (uint)(O))
        s0 = make_uint2(SLOT(ga.x, oa.x) | (SLOT(ga.y, oa.y) << 16),
                        SLOT(ga.z, oa.z) | (SLOT(ga.w, oa.w) << 16));
        s1 = make_uint2(SLOT(gb4.x, ob.x) | (SLOT(gb4.y, ob.y) << 16),
                        SLOT(gb4.z, ob.z) | (SLOT(gb4.w, ob.w) << 16));
        s2 = make_uint2(SLOT(gc.x, oc.x) | (SLOT(gc.y, oc.y) << 16),
                        SLOT(gc.z, oc.z) | (SLOT(gc.w, oc.w) << 16));
        s3 = make_uint2(SLOT(gd.x, od.x) | (SLOT(gd.y, od.y) << 16),
                        SLOT(gd.z, od.z) | (SLOT(gd.w, od.w) << 16));
#undef SLOT
    }
    __syncthreads();   // all pkl reads done; buf0 free for window-0 scatter

    // ---- r16 window loop (byte-identical) ----
    const f32x4* fe4base = (const f32x4*)(fe + bc0 * NF);
    f32x4 a0, a1, a2, a3, b0, b1, b2, b3;

    // prologue: issue pair-0 loads (channels 0,1) — plain loads (L3 hits)
    {
        const f32x4* fA = fe4base;
        const f32x4* fB = fe4base + (NF / 4);
        a0 = fA[tid]; a1 = fA[tid + 1024]; a2 = fA[tid + 2048]; a3 = fA[tl];
        b0 = fB[tid]; b1 = fB[tid + 1024]; b2 = fB[tid + 2048]; b3 = fB[tl];
    }

#define PAIR_WRITE(F, S, VA, VB) do {                                    \
        (F)[(S).x & 0xFFFFu] = cvtpk((VA)[0], (VB)[0]);                  \
        (F)[(S).x >> 16]     = cvtpk((VA)[1], (VB)[1]);                  \
        (F)[(S).y & 0xFFFFu] = cvtpk((VA)[2], (VB)[2]);                  \
        (F)[(S).y >> 16]     = cvtpk((VA)[3], (VB)[3]);                  \
    } while (0)

// Paired gather + direct coalesced NT dword stores (consecutive t across
// consecutive threads -> wave stores 256B contiguous, full lines).
#define GATHER_ST(F, P, T) do {                                          \
        uint p_ = (P);                                                   \
        uint off_ = p_ & 0x3FFFu, n_ = p_ >> 14;                         \
        float sa_ = 0.f, sb_ = 0.f;                                      \
        uint r_ = 0;                                                     \
        for (; r_ + 2 <= n_; r_ += 2) {                                  \
            uint2 w_;                                                    \
            __builtin_memcpy(&w_, &(F)[off_ + r_], 8);                   \
            sa_ += bf2f(w_.x & 0xFFFFu) + bf2f(w_.y & 0xFFFFu);          \
            sb_ += bf2f(w_.x >> 16) + bf2f(w_.y >> 16);                  \
        }                                                                \
        if (r_ < n_) {                                                   \
            uint w_ = (F)[off_ + r_];                                    \
            sa_ += bf2f(w_ & 0xFFFFu);                                   \
            sb_ += bf2f(w_ >> 16);                                       \
        }                                                                \
        float rn_ = n_ ? __builtin_amdgcn_rcpf((float)n_) : 0.f;         \
        __builtin_nontemporal_store(sa_ * rn_, &oA[T]);                  \
        __builtin_nontemporal_store(sb_ * rn_, &oB[T]);                  \
    } while (0)

#pragma unroll
    for (int k = 0; k < CPB / 2; ++k) {
        uint* F = fes32 + (k & 1) * 16000;

        // scatter pair k into buf(k&1); gather(k-1) read buf((k-1)&1) — no
        // conflict; barrier at window k-1 ordered gather(k-2) before this.
        PAIR_WRITE(F, s0, a0, b0);
        PAIR_WRITE(F, s1, a1, b1);
        PAIR_WRITE(F, s2, a2, b2);
        if (t3) PAIR_WRITE(F, s3, a3, b3);

        // prefetch next pair: uniform 8 loads, in flight across the window
        if (k + 1 < CPB / 2) {
            const f32x4* fA = fe4base + (size_t)(2 * k + 2) * (NF / 4);
            const f32x4* fB = fA + (NF / 4);
            a0 = fA[tid]; a1 = fA[tid + 1024]; a2 = fA[tid + 2048]; a3 = fA[tl];
            b0 = fB[tid]; b1 = fB[tid + 1024]; b2 = fB[tid + 2048]; b3 = fB[tl];
        }

        LGKM_BAR();   // scatter(k) visible to all; gather(k-1) complete too

        // gather + store means for both channels of pair k
        float* oA = out + (bc0 + (size_t)(2 * k)) * NT;
        float* oB = out + (bc0 + (size_t)(2 * k + 1)) * NT;
#pragma unroll
        for (int it = 0; it < 7; ++it) GATHER_ST(F, pv[it], tid + it * 1024);
        if (t8) GATHER_ST(F, pv[7], 7168 + tid);
    }
#undef GATHER_ST
#undef PAIR_WRITE
}

// Fallback (round-2 path) if workspace is too small.
__device__ __forceinline__ void lds_fadd(unsigned addr, float v) {
    asm volatile("ds_add_f32 %0, %1" :: "v"(addr), "v"(v));
}
__global__ __launch_bounds__(256) void pool_fused_kernel(const float* __restrict__ fe,
                                                         const int* __restrict__ gid,
                                                         float* __restrict__ out) {
    __shared__ float acc[NT];
    __shared__ int cnt[NT];
    const int bc = blockIdx.x, b = bc >> 8, tid = threadIdx.x;
    for (int t = tid; t < NT; t += 256) { acc[t] = 0.0f; cnt[t] = 0; }
    __syncthreads();
    const unsigned accb = (unsigned)(uintptr_t)acc;
    const float4* fe4 = (const float4*)(fe + (size_t)bc * NF);
    const int4* gid4 = (const int4*)(gid + (size_t)b * NF);
    for (int i = tid; i < NF / 4; i += 256) {
        float4 v = fe4[i];
        int4 g = gid4[i];
        lds_fadd(accb + 4u * (unsigned)g.x, v.x); atomicAdd(&cnt[g.x], 1);
        lds_fadd(accb + 4u * (unsigned)g.y, v.y); atomicAdd(&cnt[g.y], 1);
        lds_fadd(accb + 4u * (unsigned)g.z, v.z); atomicAdd(&cnt[g.z], 1);
        lds_fadd(accb + 4u * (unsigned)g.w, v.w); atomicAdd(&cnt[g.w], 1);
    }
    asm volatile("s_waitcnt lgkmcnt(0)" ::: "memory");
    __syncthreads();
    float* orow = out + (size_t)bc * NT;
    for (int t = tid; t < NT; t += 256) {
        int n = cnt[t];
        orow[t] = acc[t] / (float)(n > 0 ? n : 1);
    }
}

extern "C" void kernel_launch(void* const* d_in, const int* in_sizes, int n_in,
                              void* d_out, int out_size, void* d_ws, size_t ws_size,
                              hipStream_t stream) {
    const float* fe = (const float*)d_in[0];
    const int* gid = (const int*)d_in[1];
    float* out = (float*)d_out;

    // workspace layout (bytes)
    const size_t O_CNT = 0;          // int [NB*NT]   512000  (zeroed)
    const size_t O_OCC = 512000;     // u16 [NB*NF]   512000
    const size_t TOTAL = 1024000;

    if (ws_size >= TOTAL) {
        char* w = (char*)d_ws;
        int* cnt = (int*)(w + O_CNT);
        ushort* occ = (ushort*)(w + O_OCC);

        static bool lds_opted = false;
        if (!lds_opted) {
            (void)hipFuncSetAttribute((const void*)pool_kernel,
                                      hipFuncAttributeMaxDynamicSharedMemorySize,
                                      128000);
            lds_opted = true;
        }

        (void)hipMemsetAsync(cnt, 0, 512000, stream);
        hist_kernel<<<(NB * NF / 4 + 255) / 256, 256, 0, stream>>>(gid, cnt, occ);
        pool_kernel<<<NB * (NC / CPB), 1024, 128000, stream>>>(fe, gid, occ, cnt, out);
    } else {
        pool_fused_kernel<<<NB * NC, 256, 0, stream>>>(fe, gid, out);
    }
}